// Round 8
// baseline (276.728 us; speedup 1.0000x reference)
//
#include <hip/hip_runtime.h>
#include <stdint.h>

#define B_ 4
#define S_ 1001
#define SP 1008    // padded rows (63 * 16)
#define SPAD 1024  // padded t dimension (32 * 32)
#define EIN_ 256
#define EOUT_ 64
#define H_ 10
#define NCOL 640   // H*EOUT
#define NCOL3 1920
#define CCW 264    // chunked sc row stride in bf16 (256 + 8 pad)

typedef short bf16x8 __attribute__((ext_vector_type(8)));
typedef short bf16x4 __attribute__((ext_vector_type(4)));
typedef float f32x4 __attribute__((ext_vector_type(4)));

__device__ __forceinline__ unsigned short f2bf(float f) {
  unsigned u = __float_as_uint(f);
  u += 0x7FFFu + ((u >> 16) & 1u);  // RTNE (inputs finite)
  return (unsigned short)(u >> 16);
}
__device__ __forceinline__ float bf2f(unsigned short h) {
  return __uint_as_float(((unsigned)h) << 16);
}

// ---- kernel 1: fp32 -> bf16 (x padded, W concat, mask zero-padded bf16) ----
// vectorized x4: 638,976 groups = 2496 blocks exactly
__global__ __launch_bounds__(256) void convert_kernel(
    const float* __restrict__ x, const float* __restrict__ Wq,
    const float* __restrict__ Wk, const float* __restrict__ Wv,
    const float* __restrict__ mask, unsigned short* __restrict__ xbf,
    unsigned short* __restrict__ wbf, unsigned short* __restrict__ mbf) {
  int g = blockIdx.x * 256 + threadIdx.x;
  const int G1 = B_ * SP * EIN_ / 4;  // 258048
  const int G2 = NCOL3 * EIN_ / 4;    // 122880
  const int G3 = SP * SPAD / 4;       // 258048
  if (g < G1) {
    int i4 = g * 4;
    int b = i4 / (SP * EIN_);
    int rem = i4 % (SP * EIN_);
    int row = rem / EIN_;
    int e = rem % EIN_;
    bf16x4 o = {0, 0, 0, 0};
    if (row < S_) {
      f32x4 v = *(const f32x4*)(x + ((size_t)(b * S_ + row)) * EIN_ + e);
#pragma unroll
      for (int j = 0; j < 4; ++j) o[j] = (short)f2bf(v[j]);
    }
    *(bf16x4*)(xbf + i4) = o;
  } else if (g < G1 + G2) {
    int j4 = (g - G1) * 4;
    int col = j4 / EIN_;
    int e = j4 % EIN_;
    int mat = col / NCOL;
    int hcol = col % NCOL;
    const float* W = (mat == 0) ? Wq : (mat == 1) ? Wk : Wv;
    f32x4 v = *(const f32x4*)(W + (size_t)hcol * EIN_ + e);
    bf16x4 o;
#pragma unroll
    for (int j = 0; j < 4; ++j) o[j] = (short)f2bf(v[j]);
    *(bf16x4*)(wbf + j4) = o;
  } else if (g < G1 + G2 + G3) {
    int j4 = (g - G1 - G2) * 4;
    int row = j4 >> 10;
    int col = j4 & 1023;
    bf16x4 o = {0, 0, 0, 0};
    if (row < S_) {  // mask rows are 4004-B strided: scalar loads (coalesced)
#pragma unroll
      for (int j = 0; j < 4; ++j)
        if (col + j < S_) o[j] = (short)f2bf(mask[(size_t)row * S_ + col + j]);
    }
    *(bf16x4*)(mbf + j4) = o;
  }
}

// ---- kernel 2: projection GEMM (MFMA bf16), M=32/block, 6-way N split ----
__global__ __launch_bounds__(256, 2) void proj_kernel(
    const unsigned short* __restrict__ xbf, const unsigned short* __restrict__ wbf,
    const float* __restrict__ bq, const float* __restrict__ bk,
    const float* __restrict__ bv, unsigned short* __restrict__ qbf,
    unsigned short* __restrict__ kbf, unsigned short* __restrict__ vrow) {
  int tid = threadIdx.x;
  int wv_ = tid >> 6;
  int l = tid & 63;
  int qd = l >> 4;
  int c = l & 15;
  int bid = blockIdx.x;
  int g = bid % 6;
  int t2 = bid / 6;
  int b = t2 >> 5;
  int rg = t2 & 31;
  int s0 = rg * 32;

  bf16x8 af[2][8];
#pragma unroll
  for (int mt = 0; mt < 2; ++mt) {
    const unsigned short* xrowp = xbf + (size_t)(b * SP + s0 + mt * 16 + c) * EIN_;
#pragma unroll
    for (int ks = 0; ks < 8; ++ks)
      af[mt][ks] = *(const bf16x8*)(xrowp + ks * 32 + qd * 8);
  }

  int ntbase = g * 20 + wv_;
  const unsigned short* wp0 = wbf + (size_t)(ntbase * 16 + c) * EIN_ + qd * 8;
  bf16x8 wf[2][8];
#pragma unroll
  for (int ks = 0; ks < 8; ++ks)
    wf[0][ks] = *(const bf16x8*)(wp0 + ks * 32);

#pragma unroll
  for (int it = 0; it < 5; ++it) {
    int cur = it & 1;
    if (it < 4) {
      const unsigned short* wp = wp0 + (size_t)(it + 1) * (4 * 16 * EIN_);
#pragma unroll
      for (int ks = 0; ks < 8; ++ks)
        wf[cur ^ 1][ks] = *(const bf16x8*)(wp + ks * 32);
    }
    f32x4 acc[2] = {{0.f, 0.f, 0.f, 0.f}, {0.f, 0.f, 0.f, 0.f}};
#pragma unroll
    for (int ks = 0; ks < 8; ++ks) {
      acc[0] = __builtin_amdgcn_mfma_f32_16x16x32_bf16(af[0][ks], wf[cur][ks], acc[0], 0, 0, 0);
      acc[1] = __builtin_amdgcn_mfma_f32_16x16x32_bf16(af[1][ks], wf[cur][ks], acc[1], 0, 0, 0);
    }
    int nt = ntbase + it * 4;
    int col = nt * 16 + c;
    int mat = col / NCOL;
    int hcol = col % NCOL;
    int hh = hcol >> 6;
    int o = hcol & 63;
    const float* bias = (mat == 0) ? bq : (mat == 1) ? bk : bv;
    float bb = bias[hcol];
    unsigned short* dst = (mat == 0) ? qbf : (mat == 1) ? kbf : vrow;
    size_t base = ((size_t)(b * H_ + hh)) * SPAD * EOUT_ + o;
#pragma unroll
    for (int mt = 0; mt < 2; ++mt) {
#pragma unroll
      for (int i = 0; i < 4; ++i) {
        int srow = s0 + mt * 16 + qd * 4 + i;
        float v = (srow < S_) ? (acc[mt][i] + bb) : 0.0f;
        dst[base + (size_t)srow * EOUT_] = f2bf(v);
      }
    }
  }
}

// ---------------- kernel 3: v [t][o] -> vT [o][t] (LDS transpose) ----------------
__global__ __launch_bounds__(256) void transpose_v(
    const unsigned short* __restrict__ vrow, unsigned short* __restrict__ vT) {
  __shared__ unsigned short tl[64 * 65];
  int bid = blockIdx.x;
  int bh = bid >> 4;
  int t0 = (bid & 15) * 64;
  int tid = threadIdx.x;
#pragma unroll
  for (int i = 0; i < 16; ++i) {
    int idx = i * 256 + tid;
    int o = idx & 63;
    int t_l = idx >> 6;
    tl[o * 65 + t_l] = vrow[((size_t)bh * SPAD + t0 + t_l) * EOUT_ + o];
  }
  __syncthreads();
#pragma unroll
  for (int i = 0; i < 16; ++i) {
    int idx = i * 256 + tid;
    int t_l = idx & 63;
    int o = idx >> 6;
    vT[((size_t)bh * EOUT_ + o) * SPAD + t0 + t_l] = tl[o * 65 + t_l];
  }
}

// ---- kernel 4: attention, t-chunked (LDS 8.7 KB -> 8 blocks/CU) ----
// bid remap keeps all 63 tiles of one (b,h) on one XCD (K/V stay in its L2).
__global__ __launch_bounds__(256, 8) void attn_kernel(
    const unsigned short* __restrict__ qbf, const unsigned short* __restrict__ kbf,
    const unsigned short* __restrict__ vT, const unsigned short* __restrict__ mbf,
    float* __restrict__ rsbuf, float* __restrict__ out) {
  __shared__ unsigned short sc[16 * CCW];  // one 256-col chunk
  __shared__ float rs[16];

  int tid = threadIdx.x;
  int wv_ = tid >> 6;
  int l = tid & 63;
  int qd = l >> 4;
  int c = l & 15;
  int bid = blockIdx.x;
  int bhid = bid % 40;
  int tile = bid / 40;
  int b = bhid / 10;
  int h = bhid % 10;
  int s0 = tile * 16;

  float* concat = out;  // [B,S,640]
  size_t bh = (size_t)(b * H_ + h);
  const unsigned short* qb = qbf + bh * SPAD * EOUT_;
  const unsigned short* kb = kbf + bh * SPAD * EOUT_;
  const unsigned short* vbase =
      vT + bh * EOUT_ * SPAD + (size_t)(wv_ * 16 + c) * SPAD + qd * 8;

  bf16x8 aq0 = *(const bf16x8*)(qb + (size_t)(s0 + c) * EOUT_ + qd * 8);
  bf16x8 aq1 = *(const bf16x8*)(qb + (size_t)(s0 + c) * EOUT_ + 32 + qd * 8);

  float nacc[4] = {0.f, 0.f, 0.f, 0.f};
  f32x4 oacc = {0.f, 0.f, 0.f, 0.f};

  for (int ch = 0; ch < 4; ++ch) {
    // ---- A-chunk: scores/16 -> sc; wave wv_ owns local cols [wv_*64, +64) ----
#pragma unroll
    for (int u = 0; u < 4; ++u) {
      int lcol = wv_ * 64 + u * 16;
      const unsigned short* krow =
          kb + (size_t)(ch * 256 + lcol + c) * EOUT_ + qd * 8;
      f32x4 acc = {0.f, 0.f, 0.f, 0.f};
      acc = __builtin_amdgcn_mfma_f32_16x16x32_bf16(aq0, *(const bf16x8*)krow, acc, 0, 0, 0);
      acc = __builtin_amdgcn_mfma_f32_16x16x32_bf16(aq1, *(const bf16x8*)(krow + 32), acc, 0, 0, 0);
#pragma unroll
      for (int i = 0; i < 4; ++i)
        sc[(qd * 4 + i) * CCW + lcol + c] = f2bf(acc[i] * 0.0625f);
    }
    __syncthreads();

    // ---- B-chunk: l = exp(s)*mask; partial nacc per row (mbf zero-padded) ----
#pragma unroll
    for (int rr = 0; rr < 4; ++rr) {
      int r = wv_ * 4 + rr;
      const unsigned short* mrow = mbf + (size_t)(s0 + r) * SPAD + ch * 256;
      bf16x4 mv = *(const bf16x4*)(mrow + 4 * l);
      bf16x4 sv = *(const bf16x4*)&sc[r * CCW + 4 * l];
      bf16x4 lv;
#pragma unroll
      for (int j = 0; j < 4; ++j) {
        float e = __expf(bf2f((unsigned short)sv[j]));
        float lval = e * bf2f((unsigned short)mv[j]);
        nacc[rr] += lval * lval;
        lv[j] = (short)f2bf(lval);
      }
      *(bf16x4*)&sc[r * CCW + 4 * l] = lv;
    }
    __syncthreads();

    // ---- D-chunk: partial PV (unnormalized); wave wv_ owns o [16wv,+16) ----
#pragma unroll
    for (int ks = 0; ks < 8; ++ks) {
      bf16x8 afr = *(const bf16x8*)&sc[c * CCW + ks * 32 + qd * 8];
      bf16x8 bfr = *(const bf16x8*)(vbase + (size_t)(ch * 8 + ks) * 32);
      oacc = __builtin_amdgcn_mfma_f32_16x16x32_bf16(afr, bfr, oacc, 0, 0, 0);
    }
    __syncthreads();  // sc reused by next chunk's A
  }

  // ---- row norms: reduce nacc across 64 lanes ----
#pragma unroll
  for (int rr = 0; rr < 4; ++rr) {
    float n = nacc[rr];
    n += __shfl_xor(n, 1);
    n += __shfl_xor(n, 2);
    n += __shfl_xor(n, 4);
    n += __shfl_xor(n, 8);
    n += __shfl_xor(n, 16);
    n += __shfl_xor(n, 32);
    if (l == 0) rs[wv_ * 4 + rr] = 1.0f / fmaxf(sqrtf(n), 1e-12f);
  }
  __syncthreads();

  if (tid < 16) rsbuf[((size_t)bh * 63 + tile) * 16 + tid] = rs[tid];

#pragma unroll
  for (int i = 0; i < 4; ++i) {
    int row = qd * 4 + i;
    int srow = s0 + row;
    if (srow < S_)
      concat[((size_t)(b * S_) + srow) * NCOL + h * EOUT_ + wv_ * 16 + c] =
          oacc[i] * rs[row];
  }
}

// ---- kernel 5: wsum[b,s,t] = mask[s,t] * sum_h rs_h[s] * exp(score_h[s,t]) ----
// M=32 rows x T=256 cols per block (grid 512, 2 blocks/CU for TLP).
__global__ __launch_bounds__(256, 2) void wsum_kernel(
    const unsigned short* __restrict__ qbf, const unsigned short* __restrict__ kbf,
    const float* __restrict__ rsbuf, const unsigned short* __restrict__ mbf,
    float* __restrict__ out) {
  __shared__ float wrs[H_ * 32];
  int tid = threadIdx.x;
  int wv_ = tid >> 6;
  int l = tid & 63;
  int qd = l >> 4;
  int c = l & 15;
  int bid = blockIdx.x;
  int gid = bid & 15;   // (b, tchunk) pinned per XCD
  int rg = bid >> 4;    // 0..31
  int b = gid >> 2;
  int tchunk = gid & 3;
  int s0 = rg * 32;
  int tb = tchunk * 256 + wv_ * 64;

  for (int i = tid; i < H_ * 32; i += 256) {
    int h = i >> 5;
    int row = i & 31;
    int tile = rg * 2 + (row >> 4);
    wrs[i] = (tile < 63)
                 ? rsbuf[((size_t)(b * H_ + h) * 63 + tile) * 16 + (row & 15)]
                 : 0.0f;
  }
  __syncthreads();

  float wacc[32];
#pragma unroll
  for (int i = 0; i < 32; ++i) wacc[i] = 0.0f;

  bf16x8 qf[2][2][2], kf[2][4][2];
  {
    size_t bh0 = (size_t)(b * H_) * SPAD * EOUT_;
#pragma unroll
    for (int mt = 0; mt < 2; ++mt) {
      const unsigned short* qrow =
          qbf + bh0 + (size_t)(s0 + mt * 16 + c) * EOUT_ + qd * 8;
      qf[0][mt][0] = *(const bf16x8*)qrow;
      qf[0][mt][1] = *(const bf16x8*)(qrow + 32);
    }
#pragma unroll
    for (int st = 0; st < 4; ++st) {
      const unsigned short* krow =
          kbf + bh0 + (size_t)(tb + st * 16 + c) * EOUT_ + qd * 8;
      kf[0][st][0] = *(const bf16x8*)krow;
      kf[0][st][1] = *(const bf16x8*)(krow + 32);
    }
  }

  for (int h = 0; h < H_; ++h) {
    int sl = h & 1;
    if (h < H_ - 1) {
      size_t bh1 = (size_t)(b * H_ + h + 1) * SPAD * EOUT_;
#pragma unroll
      for (int mt = 0; mt < 2; ++mt) {
        const unsigned short* qrow =
            qbf + bh1 + (size_t)(s0 + mt * 16 + c) * EOUT_ + qd * 8;
        qf[sl ^ 1][mt][0] = *(const bf16x8*)qrow;
        qf[sl ^ 1][mt][1] = *(const bf16x8*)(qrow + 32);
      }
#pragma unroll
      for (int st = 0; st < 4; ++st) {
        const unsigned short* krow =
            kbf + bh1 + (size_t)(tb + st * 16 + c) * EOUT_ + qd * 8;
        kf[sl ^ 1][st][0] = *(const bf16x8*)krow;
        kf[sl ^ 1][st][1] = *(const bf16x8*)(krow + 32);
      }
    }
#pragma unroll
    for (int mt = 0; mt < 2; ++mt) {
      f32x4 rsv = *(const f32x4*)&wrs[h * 32 + mt * 16 + qd * 4];
#pragma unroll
      for (int st = 0; st < 4; ++st) {
        f32x4 a = {0.f, 0.f, 0.f, 0.f};
        a = __builtin_amdgcn_mfma_f32_16x16x32_bf16(qf[sl][mt][0], kf[sl][st][0], a, 0, 0, 0);
        a = __builtin_amdgcn_mfma_f32_16x16x32_bf16(qf[sl][mt][1], kf[sl][st][1], a, 0, 0, 0);
#pragma unroll
        for (int i = 0; i < 4; ++i)
          wacc[mt * 16 + st * 4 + i] += rsv[i] * __expf(a[i] * 0.0625f);
      }
    }
  }

  float* wsum = out + (size_t)B_ * S_ * NCOL;
#pragma unroll
  for (int mt = 0; mt < 2; ++mt) {
#pragma unroll
    for (int st = 0; st < 4; ++st) {
      int t = tb + st * 16 + c;
#pragma unroll
      for (int i = 0; i < 4; ++i) {
        int srow = s0 + mt * 16 + qd * 4 + i;
        if (srow < S_ && t < S_)
          wsum[((size_t)b * S_ + srow) * S_ + t] =
              wacc[mt * 16 + st * 4 + i] * bf2f(mbf[(size_t)srow * SPAD + t]);
      }
    }
  }
}

extern "C" void kernel_launch(void* const* d_in, const int* in_sizes, int n_in,
                              void* d_out, int out_size, void* d_ws, size_t ws_size,
                              hipStream_t stream) {
  const float* x = (const float*)d_in[0];
  const float* mask = (const float*)d_in[1];
  const float* Wq = (const float*)d_in[2];
  const float* bq = (const float*)d_in[3];
  const float* Wk = (const float*)d_in[4];
  const float* bk = (const float*)d_in[5];
  const float* Wv = (const float*)d_in[6];
  const float* bv = (const float*)d_in[7];
  float* out = (float*)d_out;

  char* ws = (char*)d_ws;
  const size_t NEED = 26244608;
  if (ws_size < NEED) return;  // fail cleanly rather than OOB
  unsigned short* xbf  = (unsigned short*)ws;              // 2,064,384 B
  unsigned short* wbf  = (unsigned short*)(ws + 2064384);  //   983,040 B
  unsigned short* qbf  = (unsigned short*)(ws + 3047424);  // 5,242,880 B
  unsigned short* kbf  = (unsigned short*)(ws + 8290304);  // 5,242,880 B
  unsigned short* vrow = (unsigned short*)(ws + 13533184); // 5,242,880 B
  unsigned short* vT   = (unsigned short*)(ws + 18776064); // 5,242,880 B
  unsigned short* mbf  = (unsigned short*)(ws + 24018944); // 2,064,384 B
  float*          rsbuf = (float*)(ws + 26083328);         //   161,280 B

  convert_kernel<<<2496, 256, 0, stream>>>(x, Wq, Wk, Wv, mask, xbf, wbf, mbf);
  proj_kernel<<<768, 256, 0, stream>>>(xbf, wbf, bq, bk, bv, qbf, kbf, vrow);
  transpose_v<<<640, 256, 0, stream>>>(vrow, vT);
  attn_kernel<<<2520, 256, 0, stream>>>(qbf, kbf, vT, mbf, rsbuf, out);
  wsum_kernel<<<512, 256, 0, stream>>>(qbf, kbf, rsbuf, mbf, out);
}

// Round 9
// 270.481 us; speedup vs baseline: 1.0231x; 1.0231x over previous
//
#include <hip/hip_runtime.h>
#include <stdint.h>

#define B_ 4
#define S_ 1001
#define SP 1008    // padded rows (63 * 16)
#define SPAD 1024  // padded t dimension (32 * 32)
#define EIN_ 256
#define EOUT_ 64
#define H_ 10
#define NCOL 640   // H*EOUT
#define NCOL3 1920
#define SCW 1048   // sc row stride in f16 (1024 + 24 pad)
#define SCL 0.09016844f  // 0.0625 * log2(e): exp(score/16) == exp2(score*SCL)

typedef _Float16 f16x8 __attribute__((ext_vector_type(8)));
typedef _Float16 f16x4 __attribute__((ext_vector_type(4)));
typedef float f32x4 __attribute__((ext_vector_type(4)));

#define PIN(v) asm volatile("" : "+v"(v))  // forbid load sinking/remat past here

// ---- kernel 1: fp32 -> f16 (x padded, W concat, mask zero-padded) ----
__global__ __launch_bounds__(256) void convert_kernel(
    const float* __restrict__ x, const float* __restrict__ Wq,
    const float* __restrict__ Wk, const float* __restrict__ Wv,
    const float* __restrict__ mask, _Float16* __restrict__ xhf,
    _Float16* __restrict__ whf, _Float16* __restrict__ mhf) {
  int g = blockIdx.x * 256 + threadIdx.x;
  const int G1 = B_ * SP * EIN_ / 4;  // 258048
  const int G2 = NCOL3 * EIN_ / 4;    // 122880
  const int G3 = SP * SPAD / 4;       // 258048
  if (g < G1) {
    int i4 = g * 4;
    int b = i4 / (SP * EIN_);
    int rem = i4 % (SP * EIN_);
    int row = rem / EIN_;
    int e = rem % EIN_;
    f16x4 o = {0, 0, 0, 0};
    if (row < S_) {
      f32x4 v = *(const f32x4*)(x + ((size_t)(b * S_ + row)) * EIN_ + e);
#pragma unroll
      for (int j = 0; j < 4; ++j) o[j] = (_Float16)v[j];
    }
    *(f16x4*)(xhf + i4) = o;
  } else if (g < G1 + G2) {
    int j4 = (g - G1) * 4;
    int col = j4 / EIN_;
    int e = j4 % EIN_;
    int mat = col / NCOL;
    int hcol = col % NCOL;
    const float* W = (mat == 0) ? Wq : (mat == 1) ? Wk : Wv;
    f32x4 v = *(const f32x4*)(W + (size_t)hcol * EIN_ + e);
    f16x4 o;
#pragma unroll
    for (int j = 0; j < 4; ++j) o[j] = (_Float16)v[j];
    *(f16x4*)(whf + j4) = o;
  } else if (g < G1 + G2 + G3) {
    int j4 = (g - G1 - G2) * 4;
    int row = j4 >> 10;
    int col = j4 & 1023;
    f16x4 o = {0, 0, 0, 0};
    if (row < S_) {
#pragma unroll
      for (int j = 0; j < 4; ++j)
        if (col + j < S_) o[j] = (_Float16)mask[(size_t)row * S_ + col + j];
    }
    *(f16x4*)(mhf + j4) = o;
  }
}

// ---- kernel 2: projection GEMM (MFMA f16), M=32/block, 6-way N split ----
__global__ __launch_bounds__(256, 2) void proj_kernel(
    const _Float16* __restrict__ xhf, const _Float16* __restrict__ whf,
    const float* __restrict__ bq, const float* __restrict__ bk,
    const float* __restrict__ bv, _Float16* __restrict__ qhf,
    _Float16* __restrict__ khf, _Float16* __restrict__ vrow) {
  int tid = threadIdx.x;
  int wv_ = tid >> 6;
  int l = tid & 63;
  int qd = l >> 4;
  int c = l & 15;
  int bid = blockIdx.x;
  int g = bid % 6;
  int t2 = bid / 6;
  int b = t2 >> 5;
  int rg = t2 & 31;
  int s0 = rg * 32;

  f16x8 af[2][8];
#pragma unroll
  for (int mt = 0; mt < 2; ++mt) {
    const _Float16* xrowp = xhf + (size_t)(b * SP + s0 + mt * 16 + c) * EIN_;
#pragma unroll
    for (int ks = 0; ks < 8; ++ks) {
      af[mt][ks] = *(const f16x8*)(xrowp + ks * 32 + qd * 8);
      PIN(af[mt][ks]);
    }
  }

  int ntbase = g * 20 + wv_;
  const _Float16* wp0 = whf + (size_t)(ntbase * 16 + c) * EIN_ + qd * 8;
  f16x8 wf[2][8];
#pragma unroll
  for (int ks = 0; ks < 8; ++ks) {
    wf[0][ks] = *(const f16x8*)(wp0 + ks * 32);
    PIN(wf[0][ks]);
  }

#pragma unroll
  for (int it = 0; it < 5; ++it) {
    int cur = it & 1;
    if (it < 4) {
      const _Float16* wp = wp0 + (size_t)(it + 1) * (4 * 16 * EIN_);
#pragma unroll
      for (int ks = 0; ks < 8; ++ks) {
        wf[cur ^ 1][ks] = *(const f16x8*)(wp + ks * 32);
        PIN(wf[cur ^ 1][ks]);
      }
    }
    f32x4 acc[2] = {{0.f, 0.f, 0.f, 0.f}, {0.f, 0.f, 0.f, 0.f}};
#pragma unroll
    for (int ks = 0; ks < 8; ++ks) {
      acc[0] = __builtin_amdgcn_mfma_f32_16x16x32_f16(af[0][ks], wf[cur][ks], acc[0], 0, 0, 0);
      acc[1] = __builtin_amdgcn_mfma_f32_16x16x32_f16(af[1][ks], wf[cur][ks], acc[1], 0, 0, 0);
    }
    int nt = ntbase + it * 4;
    int col = nt * 16 + c;
    int mat = col / NCOL;
    int hcol = col % NCOL;
    int hh = hcol >> 6;
    int o = hcol & 63;
    const float* bias = (mat == 0) ? bq : (mat == 1) ? bk : bv;
    float bb = bias[hcol];
    _Float16* dst = (mat == 0) ? qhf : (mat == 1) ? khf : vrow;
    size_t base = ((size_t)(b * H_ + hh)) * SPAD * EOUT_ + o;
#pragma unroll
    for (int mt = 0; mt < 2; ++mt) {
#pragma unroll
      for (int i = 0; i < 4; ++i) {
        int srow = s0 + mt * 16 + qd * 4 + i;
        float v = (srow < S_) ? (acc[mt][i] + bb) : 0.0f;
        dst[base + (size_t)srow * EOUT_] = (_Float16)v;
      }
    }
  }
}

// ---------------- kernel 3: v [t][o] -> vT [o][t] (LDS transpose) ----------------
__global__ __launch_bounds__(256) void transpose_v(
    const unsigned short* __restrict__ vrow, unsigned short* __restrict__ vT) {
  __shared__ unsigned short tl[64 * 65];
  int bid = blockIdx.x;
  int bh = bid >> 4;
  int t0 = (bid & 15) * 64;
  int tid = threadIdx.x;
#pragma unroll
  for (int i = 0; i < 16; ++i) {
    int idx = i * 256 + tid;
    int o = idx & 63;
    int t_l = idx >> 6;
    tl[o * 65 + t_l] = vrow[((size_t)bh * SPAD + t0 + t_l) * EOUT_ + o];
  }
  __syncthreads();
#pragma unroll
  for (int i = 0; i < 16; ++i) {
    int idx = i * 256 + tid;
    int t_l = idx & 63;
    int o = idx >> 6;
    vT[((size_t)bh * EOUT_ + o) * SPAD + t0 + t_l] = tl[o * 65 + t_l];
  }
}

// ---- kernel 4: attention (r7 structure + pinned prefetch rings, f16, exp2) ----
// bid remap keeps all 63 tiles of one (b,h) on one XCD (K/V stay in its L2).
__global__ __launch_bounds__(256, 4) void attn_kernel(
    const _Float16* __restrict__ qhf, const _Float16* __restrict__ khf,
    const _Float16* __restrict__ vT, const _Float16* __restrict__ mhf,
    float* __restrict__ rsbuf, float* __restrict__ out) {
  __shared__ _Float16 sc[16 * SCW];
  __shared__ float rs[16];

  int tid = threadIdx.x;
  int wv_ = tid >> 6;
  int l = tid & 63;
  int qd = l >> 4;
  int c = l & 15;
  int bid = blockIdx.x;
  int bhid = bid % 40;
  int tile = bid / 40;
  int b = bhid / 10;
  int h = bhid % 10;
  int s0 = tile * 16;

  if (tid < 16) rs[tid] = 0.0f;

  float* concat = out;  // [B,S,640]
  size_t bh = (size_t)(b * H_ + h);
  const _Float16* qb = qhf + bh * SPAD * EOUT_;
  const _Float16* kb = khf + bh * SPAD * EOUT_;
  const _Float16* vbase =
      vT + bh * EOUT_ * SPAD + (size_t)(wv_ * 16 + c) * SPAD + qd * 8;

  // early vT prefetch ring (pinned -> stays in flight across phases A/B)
  f16x8 bpre[8];
#pragma unroll
  for (int p = 0; p < 8; ++p) {
    bpre[p] = *(const f16x8*)(vbase + p * 32);
    PIN(bpre[p]);
  }

  f16x8 aq0 = *(const f16x8*)(qb + (size_t)(s0 + c) * EOUT_ + qd * 8);
  f16x8 aq1 = *(const f16x8*)(qb + (size_t)(s0 + c) * EOUT_ + 32 + qd * 8);
  PIN(aq0);
  PIN(aq1);

  // ---- phase A: s' = score*SCL -> sc; wave wv_ owns t in [wv_*256, +256) ----
  const _Float16* kbase = kb + (size_t)(wv_ * 256 + c) * EOUT_ + qd * 8;
  f16x8 kq[4][2];  // depth-4 pinned ring
#pragma unroll
  for (int p = 0; p < 4; ++p) {
    kq[p][0] = *(const f16x8*)(kbase + (size_t)p * 16 * EOUT_);
    kq[p][1] = *(const f16x8*)(kbase + (size_t)p * 16 * EOUT_ + 32);
    PIN(kq[p][0]);
    PIN(kq[p][1]);
  }
#pragma unroll
  for (int u = 0; u < 16; ++u) {
    int slot = u & 3;
    f32x4 acc = {0.f, 0.f, 0.f, 0.f};
    acc = __builtin_amdgcn_mfma_f32_16x16x32_f16(aq0, kq[slot][0], acc, 0, 0, 0);
    acc = __builtin_amdgcn_mfma_f32_16x16x32_f16(aq1, kq[slot][1], acc, 0, 0, 0);
    if (u < 12) {
      kq[slot][0] = *(const f16x8*)(kbase + (size_t)(u + 4) * 16 * EOUT_);
      kq[slot][1] = *(const f16x8*)(kbase + (size_t)(u + 4) * 16 * EOUT_ + 32);
      PIN(kq[slot][0]);
      PIN(kq[slot][1]);
    }
    int t0 = wv_ * 256 + u * 16;
#pragma unroll
    for (int i = 0; i < 4; ++i)
      sc[(qd * 4 + i) * SCW + t0 + c] = (_Float16)(acc[i] * SCL);
  }
  __syncthreads();

  // ---- phase B: l = exp2(s')*mask; row-per-wave, coalesced (mhf zero-padded) ----
#pragma unroll
  for (int rr = 0; rr < 4; ++rr) {
    int r = wv_ * 4 + rr;
    int srow = s0 + r;
    if (srow < S_) {  // wave-uniform branch
      const _Float16* mrow = mhf + (size_t)srow * SPAD;
      f16x8 mv0 = *(const f16x8*)(mrow + 8 * l);
      f16x8 mv1 = *(const f16x8*)(mrow + 512 + 8 * l);
      f16x8 sv0 = *(const f16x8*)&sc[r * SCW + 8 * l];
      f16x8 sv1 = *(const f16x8*)&sc[r * SCW + 512 + 8 * l];
      float nacc = 0.0f;
      f16x8 lv0, lv1;
#pragma unroll
      for (int j = 0; j < 8; ++j) {
        float e = exp2f((float)sv0[j]);
        float lval = e * (float)mv0[j];
        nacc += lval * lval;
        lv0[j] = (_Float16)lval;
      }
#pragma unroll
      for (int j = 0; j < 8; ++j) {
        float e = exp2f((float)sv1[j]);
        float lval = e * (float)mv1[j];
        nacc += lval * lval;
        lv1[j] = (_Float16)lval;
      }
      *(f16x8*)&sc[r * SCW + 8 * l] = lv0;
      *(f16x8*)&sc[r * SCW + 512 + 8 * l] = lv1;
      nacc += __shfl_xor(nacc, 1);
      nacc += __shfl_xor(nacc, 2);
      nacc += __shfl_xor(nacc, 4);
      nacc += __shfl_xor(nacc, 8);
      nacc += __shfl_xor(nacc, 16);
      nacc += __shfl_xor(nacc, 32);
      if (l == 0) rs[r] = 1.0f / fmaxf(sqrtf(nacc), 1e-12f);
    }
  }
  __syncthreads();

  if (tid < 16) rsbuf[((size_t)bh * 63 + tile) * 16 + tid] = rs[tid];

  // ---- phase D: out = (l V) * rs[row]; rolling pinned 8-deep vT ring ----
  f32x4 oacc = {0.f, 0.f, 0.f, 0.f};
#pragma unroll
  for (int kstep = 0; kstep < 32; ++kstep) {
    int slot = kstep & 7;
    f16x8 afr = *(const f16x8*)&sc[c * SCW + kstep * 32 + qd * 8];
    oacc = __builtin_amdgcn_mfma_f32_16x16x32_f16(afr, bpre[slot], oacc, 0, 0, 0);
    if (kstep < 24) {
      bpre[slot] = *(const f16x8*)(vbase + (size_t)(kstep + 8) * 32);
      PIN(bpre[slot]);
    }
  }
#pragma unroll
  for (int i = 0; i < 4; ++i) {
    int row = qd * 4 + i;
    int srow = s0 + row;
    if (srow < S_)
      concat[((size_t)(b * S_) + srow) * NCOL + h * EOUT_ + wv_ * 16 + c] =
          oacc[i] * rs[row];
  }
}

// ---- kernel 5: wsum[b,s,t] = mask[s,t] * sum_h rs_h[s] * exp2(score_h*SCL) ----
// M=32 rows x T=256 cols per block (grid 512, 2 blocks/CU), pinned dbuf, h unrolled.
__global__ __launch_bounds__(256, 2) void wsum_kernel(
    const _Float16* __restrict__ qhf, const _Float16* __restrict__ khf,
    const float* __restrict__ rsbuf, const _Float16* __restrict__ mhf,
    float* __restrict__ out) {
  __shared__ float wrs[H_ * 32];
  int tid = threadIdx.x;
  int wv_ = tid >> 6;
  int l = tid & 63;
  int qd = l >> 4;
  int c = l & 15;
  int bid = blockIdx.x;
  int gid = bid & 15;   // (b, tchunk) pinned per XCD
  int rg = bid >> 4;    // 0..31
  int b = gid >> 2;
  int tchunk = gid & 3;
  int s0 = rg * 32;
  int tb = tchunk * 256 + wv_ * 64;

  for (int i = tid; i < H_ * 32; i += 256) {
    int h = i >> 5;
    int row = i & 31;
    int tile = rg * 2 + (row >> 4);
    wrs[i] = (tile < 63)
                 ? rsbuf[((size_t)(b * H_ + h) * 63 + tile) * 16 + (row & 15)]
                 : 0.0f;
  }
  __syncthreads();

  float wacc[32];
#pragma unroll
  for (int i = 0; i < 32; ++i) wacc[i] = 0.0f;

  f16x8 qf[2][2][2], kf[2][4][2];
  {
    size_t bh0 = (size_t)(b * H_) * SPAD * EOUT_;
#pragma unroll
    for (int mt = 0; mt < 2; ++mt) {
      const _Float16* qrow = qhf + bh0 + (size_t)(s0 + mt * 16 + c) * EOUT_ + qd * 8;
      qf[0][mt][0] = *(const f16x8*)qrow;
      qf[0][mt][1] = *(const f16x8*)(qrow + 32);
      PIN(qf[0][mt][0]);
      PIN(qf[0][mt][1]);
    }
#pragma unroll
    for (int st = 0; st < 4; ++st) {
      const _Float16* krow = khf + bh0 + (size_t)(tb + st * 16 + c) * EOUT_ + qd * 8;
      kf[0][st][0] = *(const f16x8*)krow;
      kf[0][st][1] = *(const f16x8*)(krow + 32);
      PIN(kf[0][st][0]);
      PIN(kf[0][st][1]);
    }
  }

#pragma unroll
  for (int h = 0; h < H_; ++h) {
    int sl = h & 1;
    if (h < H_ - 1) {
      size_t bh1 = (size_t)(b * H_ + h + 1) * SPAD * EOUT_;
#pragma unroll
      for (int mt = 0; mt < 2; ++mt) {
        const _Float16* qrow = qhf + bh1 + (size_t)(s0 + mt * 16 + c) * EOUT_ + qd * 8;
        qf[sl ^ 1][mt][0] = *(const f16x8*)qrow;
        qf[sl ^ 1][mt][1] = *(const f16x8*)(qrow + 32);
        PIN(qf[sl ^ 1][mt][0]);
        PIN(qf[sl ^ 1][mt][1]);
      }
#pragma unroll
      for (int st = 0; st < 4; ++st) {
        const _Float16* krow = khf + bh1 + (size_t)(tb + st * 16 + c) * EOUT_ + qd * 8;
        kf[sl ^ 1][st][0] = *(const f16x8*)krow;
        kf[sl ^ 1][st][1] = *(const f16x8*)(krow + 32);
        PIN(kf[sl ^ 1][st][0]);
        PIN(kf[sl ^ 1][st][1]);
      }
    }
#pragma unroll
    for (int mt = 0; mt < 2; ++mt) {
      f32x4 rsv = *(const f32x4*)&wrs[h * 32 + mt * 16 + qd * 4];
#pragma unroll
      for (int st = 0; st < 4; ++st) {
        f32x4 a = {0.f, 0.f, 0.f, 0.f};
        a = __builtin_amdgcn_mfma_f32_16x16x32_f16(qf[sl][mt][0], kf[sl][st][0], a, 0, 0, 0);
        a = __builtin_amdgcn_mfma_f32_16x16x32_f16(qf[sl][mt][1], kf[sl][st][1], a, 0, 0, 0);
#pragma unroll
        for (int i = 0; i < 4; ++i)
          wacc[mt * 16 + st * 4 + i] += rsv[i] * exp2f(a[i] * SCL);
      }
    }
  }

  float* wsum = out + (size_t)B_ * S_ * NCOL;
#pragma unroll
  for (int mt = 0; mt < 2; ++mt) {
#pragma unroll
    for (int st = 0; st < 4; ++st) {
      int t = tb + st * 16 + c;
#pragma unroll
      for (int i = 0; i < 4; ++i) {
        int srow = s0 + mt * 16 + qd * 4 + i;
        if (srow < S_ && t < S_)
          wsum[((size_t)b * S_ + srow) * S_ + t] =
              wacc[mt * 16 + st * 4 + i] * (float)mhf[(size_t)srow * SPAD + t];
      }
    }
  }
}

extern "C" void kernel_launch(void* const* d_in, const int* in_sizes, int n_in,
                              void* d_out, int out_size, void* d_ws, size_t ws_size,
                              hipStream_t stream) {
  const float* x = (const float*)d_in[0];
  const float* mask = (const float*)d_in[1];
  const float* Wq = (const float*)d_in[2];
  const float* bq = (const float*)d_in[3];
  const float* Wk = (const float*)d_in[4];
  const float* bk = (const float*)d_in[5];
  const float* Wv = (const float*)d_in[6];
  const float* bv = (const float*)d_in[7];
  float* out = (float*)d_out;

  char* ws = (char*)d_ws;
  const size_t NEED = 26244608;
  if (ws_size < NEED) return;  // fail cleanly rather than OOB
  _Float16* xhf  = (_Float16*)ws;              // 2,064,384 B
  _Float16* whf  = (_Float16*)(ws + 2064384);  //   983,040 B
  _Float16* qhf  = (_Float16*)(ws + 3047424);  // 5,242,880 B
  _Float16* khf  = (_Float16*)(ws + 8290304);  // 5,242,880 B
  _Float16* vrow = (_Float16*)(ws + 13533184); // 5,242,880 B
  _Float16* vT   = (_Float16*)(ws + 18776064); // 5,242,880 B
  _Float16* mhf  = (_Float16*)(ws + 24018944); // 2,064,384 B
  float*    rsbuf = (float*)(ws + 26083328);   //   161,280 B

  convert_kernel<<<2496, 256, 0, stream>>>(x, Wq, Wk, Wv, mask, xhf, whf, mhf);
  proj_kernel<<<768, 256, 0, stream>>>(xhf, whf, bq, bk, bv, qhf, khf, vrow);
  transpose_v<<<640, 256, 0, stream>>>((const unsigned short*)vrow,
                                       (unsigned short*)vT);
  attn_kernel<<<2520, 256, 0, stream>>>(qhf, khf, vT, mhf, rsbuf, out);
  wsum_kernel<<<512, 256, 0, stream>>>(qhf, khf, rsbuf, mhf, out);
}